// Round 9
// baseline (943.479 us; speedup 1.0000x reference)
//
#include <hip/hip_runtime.h>
#include <math.h>

#define S_LEN 2048
#define NH 16
#define HDIM 64
#define BATCH 2
#define BHC 32          // BATCH*NH
#define KK 409          // int(2048 * (1.0 - 0.8)) per reference float math
#define DMODEL 1024

typedef __attribute__((ext_vector_type(8))) short bf16x8;   // 8 bf16 in 4 VGPRs
typedef __attribute__((ext_vector_type(4))) float f32x4;

#define SC_STRW 2056    // fp32 score row stride in words (bank rot 8: writes 4-way, reads 2-way)
#define P_STR   2064    // bf16 P row stride (4128 B rows, 16B-aligned; PV reads 4-way)
#define T_STR   40      // bf16 LDS tile row stride for gemm (16B-aligned, 2-way free)

__device__ __forceinline__ unsigned f2ord(float f) {
    unsigned u = __float_as_uint(f);
    return (u & 0x80000000u) ? ~u : (u | 0x80000000u);
}
__device__ __forceinline__ float ord2f(unsigned v) {
    unsigned u = (v & 0x80000000u) ? (v & 0x7fffffffu) : ~v;
    return __uint_as_float(u);
}
__device__ __forceinline__ unsigned short f2bf(float f) {   // RNE
    unsigned u = __float_as_uint(f);
    u += 0x7fffu + ((u >> 16) & 1u);
    return (unsigned short)(u >> 16);
}
__device__ __forceinline__ float bf2f(unsigned short h) {
    return __uint_as_float(((unsigned)h) << 16);
}

// ---------------------------------------------------------------------------
// fp32 -> bf16 hi/lo split (vectorized float4 / ushort4), n4 = elements/4
// ---------------------------------------------------------------------------
__global__ __launch_bounds__(256)
void split32(const float* __restrict__ in, unsigned short* __restrict__ hi,
             unsigned short* __restrict__ lo, int n4)
{
    const int i = blockIdx.x * 256 + threadIdx.x;
    if (i < n4) {
        const float4 v = ((const float4*)in)[i];
        ushort4 h, l;
        h.x = f2bf(v.x); l.x = f2bf(v.x - bf2f(h.x));
        h.y = f2bf(v.y); l.y = f2bf(v.y - bf2f(h.y));
        h.z = f2bf(v.z); l.z = f2bf(v.z - bf2f(h.z));
        h.w = f2bf(v.w); l.w = f2bf(v.w - bf2f(h.w));
        ((ushort4*)hi)[i] = h;
        ((ushort4*)lo)[i] = l;
    }
}

// ---------------------------------------------------------------------------
// LDS-staged split-bf16 3-pass MFMA GEMM (unchanged from R8 — banked).
//   C[m][n] = sum_k A[m][k]*B[n][k] + bias[n]
// ---------------------------------------------------------------------------
__global__ __launch_bounds__(256)
void gemm_mfma(const unsigned short* __restrict__ Ah, const unsigned short* __restrict__ Al,
               const unsigned short* __restrict__ Bh, const unsigned short* __restrict__ Bl,
               const float* __restrict__ bias, void* __restrict__ out0,
               void* __restrict__ out1, int mode)
{
    __shared__ __align__(16) unsigned short sAh[128 * T_STR];
    __shared__ __align__(16) unsigned short sAl[128 * T_STR];
    __shared__ __align__(16) unsigned short sBh[64 * T_STR];
    __shared__ __align__(16) unsigned short sBl[64 * T_STR];

    const int tid  = threadIdx.x;
    const int lane = tid & 63;
    const int w    = tid >> 6;
    const int q15  = lane & 15;
    const int quad = lane >> 4;
    const int n0b = blockIdx.x * 64;
    const int m0b = blockIdx.y * 128;
    const int wm = (w >> 1) * 64;
    const int wn = (w & 1) * 32;

    const int ar0 = tid >> 2, aks0 = (tid & 3) * 8;
    const int ar1 = (tid + 256) >> 2, aks1 = aks0;
    const int br = tid >> 2, bks = (tid & 3) * 8;

    const unsigned short* gAh0 = Ah + (size_t)(m0b + ar0) * 1024 + aks0;
    const unsigned short* gAh1 = Ah + (size_t)(m0b + ar1) * 1024 + aks1;
    const unsigned short* gAl0 = Al + (size_t)(m0b + ar0) * 1024 + aks0;
    const unsigned short* gAl1 = Al + (size_t)(m0b + ar1) * 1024 + aks1;
    const unsigned short* gBh = Bh + (size_t)(n0b + br) * 1024 + bks;
    const unsigned short* gBl = Bl + (size_t)(n0b + br) * 1024 + bks;

    f32x4 acc[4][2];
#pragma unroll
    for (int mt = 0; mt < 4; ++mt)
#pragma unroll
        for (int nt = 0; nt < 2; ++nt) acc[mt][nt] = (f32x4){0.f, 0.f, 0.f, 0.f};

#pragma unroll 1
    for (int k0 = 0; k0 < 1024; k0 += 32) {
        const bf16x8 vah0 = *(const bf16x8*)(gAh0 + k0);
        const bf16x8 vah1 = *(const bf16x8*)(gAh1 + k0);
        const bf16x8 val0 = *(const bf16x8*)(gAl0 + k0);
        const bf16x8 val1 = *(const bf16x8*)(gAl1 + k0);
        const bf16x8 vbh  = *(const bf16x8*)(gBh + k0);
        const bf16x8 vbl  = *(const bf16x8*)(gBl + k0);
        __syncthreads();
        *(bf16x8*)(sAh + ar0 * T_STR + aks0) = vah0;
        *(bf16x8*)(sAh + ar1 * T_STR + aks1) = vah1;
        *(bf16x8*)(sAl + ar0 * T_STR + aks0) = val0;
        *(bf16x8*)(sAl + ar1 * T_STR + aks1) = val1;
        *(bf16x8*)(sBh + br * T_STR + bks) = vbh;
        *(bf16x8*)(sBl + br * T_STR + bks) = vbl;
        __syncthreads();

        bf16x8 fbh[2], fbl[2];
#pragma unroll
        for (int nt = 0; nt < 2; ++nt) {
            fbh[nt] = *(const bf16x8*)(sBh + (wn + nt * 16 + q15) * T_STR + quad * 8);
            fbl[nt] = *(const bf16x8*)(sBl + (wn + nt * 16 + q15) * T_STR + quad * 8);
        }
#pragma unroll
        for (int mt = 0; mt < 4; ++mt) {
            const bf16x8 fah = *(const bf16x8*)(sAh + (wm + mt * 16 + q15) * T_STR + quad * 8);
            const bf16x8 fal = *(const bf16x8*)(sAl + (wm + mt * 16 + q15) * T_STR + quad * 8);
#pragma unroll
            for (int nt = 0; nt < 2; ++nt) {
                acc[mt][nt] = __builtin_amdgcn_mfma_f32_16x16x32_bf16(fah, fbh[nt], acc[mt][nt], 0, 0, 0);
                acc[mt][nt] = __builtin_amdgcn_mfma_f32_16x16x32_bf16(fah, fbl[nt], acc[mt][nt], 0, 0, 0);
                acc[mt][nt] = __builtin_amdgcn_mfma_f32_16x16x32_bf16(fal, fbh[nt], acc[mt][nt], 0, 0, 0);
            }
        }
    }

#pragma unroll
    for (int nt = 0; nt < 2; ++nt) {
        const int n = n0b + wn + nt * 16 + q15;
        const float bv = bias[n];
#pragma unroll
        for (int mt = 0; mt < 4; ++mt) {
            const int mb = m0b + wm + mt * 16 + quad * 4;
#pragma unroll
            for (int rg = 0; rg < 4; ++rg) {
                const int m = mb + rg;
                const float o = acc[mt][nt][rg] + bv;
                if (mode == 0) {
                    ((float*)out0)[(size_t)m * 1024 + n] = o;
                } else {
                    const int b = m >> 11, s = m & 2047;
                    const int h = n >> 6, hd = n & 63;
                    const size_t base = ((size_t)((b * NH + h) * S_LEN + s)) * HDIM + hd;
                    if (mode == 3) {
                        ((unsigned short*)out0)[base] = f2bf(o);
                    } else {
                        const unsigned short oh = f2bf(o);
                        ((unsigned short*)out0)[base] = oh;
                        ((unsigned short*)out1)[base] = f2bf(o - bf2f(oh));
                    }
                }
            }
        }
    }
}

// ---------------------------------------------------------------------------
// V bf16 [bh][s][64] -> Vt bf16 [bh][64][2048]  (B-operand layout for PV MFMA)
// ---------------------------------------------------------------------------
__global__ __launch_bounds__(256)
void transpose_v16(const unsigned short* __restrict__ V, unsigned short* __restrict__ Vt)
{
    __shared__ unsigned short t[64][72];
    const int tid = threadIdx.x;
    const int s0 = blockIdx.x * 64;
    const int bh = blockIdx.y;
    const unsigned short* Vb = V + (size_t)bh * S_LEN * HDIM;
#pragma unroll
    for (int i = 0; i < 4; ++i) {
        const int f = tid + i * 256;
        const int s = f >> 4;
        const int hq = (f & 15) * 4;
        const ushort4 v = *(const ushort4*)(Vb + (size_t)(s0 + s) * HDIM + hq);
        t[s][hq + 0] = v.x; t[s][hq + 1] = v.y; t[s][hq + 2] = v.z; t[s][hq + 3] = v.w;
    }
    __syncthreads();
    unsigned short* Vtb = Vt + (size_t)bh * HDIM * S_LEN;
#pragma unroll
    for (int i = 0; i < 4; ++i) {
        const int f = tid + i * 256;
        const int hd = f >> 4;
        const int sq = (f & 15) * 4;
        ushort4 v;
        v.x = t[sq + 0][hd]; v.y = t[sq + 1][hd];
        v.z = t[sq + 2][hd]; v.w = t[sq + 3][hd];
        *(ushort4*)(Vtb + (size_t)hd * S_LEN + s0 + sq) = v;
    }
}

// ---------------------------------------------------------------------------
// Exact 409th-largest over 2048 ordered uints held as u[32] per lane.
// Constant indices only (by-reference array) -> stays in VGPRs.
// Early exit: when candidate count == rem, answer = min over candidates.
// ---------------------------------------------------------------------------
__device__ __forceinline__ unsigned radix_select(const unsigned (&u)[32])
{
    unsigned T = 0;
    int rem = KK;
    int C = 2048;
#pragma unroll 1
    for (int b = 31; b >= 0; --b) {
        const unsigned want = (T >> b) | 1u;
        int cnt = 0;
#pragma unroll
        for (int i = 0; i < 32; ++i)
            cnt += __builtin_popcountll(__ballot((u[i] >> b) == want));
        if (cnt >= rem) { T |= (1u << b); C = cnt; }
        else { rem -= cnt; C -= cnt; }
        if (C == rem) {
            const unsigned pre = T >> b;
            unsigned mn = 0xffffffffu;
#pragma unroll
            for (int i = 0; i < 32; ++i) {
                const unsigned v = ((u[i] >> b) == pre) ? u[i] : 0xffffffffu;
                mn = v < mn ? v : mn;
            }
#pragma unroll
            for (int off = 32; off >= 1; off >>= 1) {
                const unsigned o = (unsigned)__shfl_xor((int)mn, off);
                mn = o < mn ? o : mn;
            }
            return mn;
        }
    }
    return T;
}

// ---------------------------------------------------------------------------
// Fused attention v7: 1024 threads / 16 waves; block = (bh, 16 q-rows).
// ONE q-row per wave -> u[32] only (32 VGPRs, constant-indexed, no runtime
// pointer selects) -> no scratch spill.
//  phase 1: wave w computes score cols [128w,128w+128) for all 16 q-rows
//           (8 tiles x 6 split-bf16 MFMA), writes full sc[16][2056w] in LDS.
//  barrier; wave w reads ITS row w into u[32]; barrier (sc dead).
//  phase 2: per-wave exact radix select + exp -> P bf16 row w (no barriers
//           between waves needed until PV).
//  barrier; phase 3: wave w does PV for keys [128w,+128) over all 16 q
//           (16 MFMA) -> Opart[w]; barrier; 16-way reduce, bf16 hi/lo out.
// LDS 131,584 B: sc[16][2056]f32  overlaid by  P[16][2064]bf16 (66,048 B,
// offset 0) + Opart[16][16][64]f32 (65,536 B, offset 66,048) - disjoint.
// 1 block/CU, 4 waves/SIMD, VGPR capped 128 (est. peak ~85).
// ---------------------------------------------------------------------------
__global__ __launch_bounds__(1024, 4)
void attn_kernel(const unsigned short* __restrict__ Qh, const unsigned short* __restrict__ Ql,
                 const unsigned short* __restrict__ Kh, const unsigned short* __restrict__ Kl,
                 const unsigned short* __restrict__ Vt,
                 unsigned short* __restrict__ AOh, unsigned short* __restrict__ AOl)
{
    extern __shared__ __align__(16) char smem[];
    float* sc = (float*)smem;                            // [16][SC_STRW] f32
    unsigned short* P = (unsigned short*)smem;           // overlay [16][P_STR] bf16
    float* Opart = (float*)(smem + 66048);               // [16][16][64] f32

    const int tid  = threadIdx.x;
    const int lane = tid & 63;
    const int w    = tid >> 6;        // wave id == owned q-row
    const int q15  = lane & 15;
    const int quad = lane >> 4;

    // XCD swizzle: each XCD works one head at a time (128 consecutive
    // q-groups per head) -> K/Q/Vt working set ~1.75 MB, L2-resident.
    const int blk = blockIdx.x;
    const int xcd = blk & 7;
    const int j   = blk >> 3;              // 0..511
    const int bh  = xcd * 4 + (j >> 7);    // 0..31
    const int q0  = (j & 127) * 16;        // 0..2032

    // ---- Q B-frags direct from global ----
    const size_t qrow = ((size_t)bh * S_LEN + q0 + q15) * HDIM;
    const bf16x8 bqh0 = *(const bf16x8*)(Qh + qrow + quad * 8);
    const bf16x8 bqh1 = *(const bf16x8*)(Qh + qrow + 32 + quad * 8);
    const bf16x8 bql0 = *(const bf16x8*)(Ql + qrow + quad * 8);
    const bf16x8 bql1 = *(const bf16x8*)(Ql + qrow + 32 + quad * 8);

    const size_t kbase = (size_t)bh * S_LEN * HDIM;

    // ---- phase 1: scores for key-span [128w, 128w+128), all 16 q-rows ----
#pragma unroll 2
    for (int t = 0; t < 8; ++t) {
        const int key = w * 128 + t * 16 + q15;            // A-frag m
        const unsigned short* kh = Kh + kbase + (size_t)key * HDIM + quad * 8;
        const unsigned short* kl = Kl + kbase + (size_t)key * HDIM + quad * 8;
        const bf16x8 akh0 = *(const bf16x8*)(kh);
        const bf16x8 akh1 = *(const bf16x8*)(kh + 32);
        const bf16x8 akl0 = *(const bf16x8*)(kl);
        const bf16x8 akl1 = *(const bf16x8*)(kl + 32);
        f32x4 c = {0.f, 0.f, 0.f, 0.f};
        c = __builtin_amdgcn_mfma_f32_16x16x32_bf16(akh0, bqh0, c, 0, 0, 0);
        c = __builtin_amdgcn_mfma_f32_16x16x32_bf16(akh1, bqh1, c, 0, 0, 0);
        c = __builtin_amdgcn_mfma_f32_16x16x32_bf16(akh0, bql0, c, 0, 0, 0);
        c = __builtin_amdgcn_mfma_f32_16x16x32_bf16(akh1, bql1, c, 0, 0, 0);
        c = __builtin_amdgcn_mfma_f32_16x16x32_bf16(akl0, bqh0, c, 0, 0, 0);
        c = __builtin_amdgcn_mfma_f32_16x16x32_bf16(akl1, bqh1, c, 0, 0, 0);
        // C-layout: col(lane&15)=q, row(quad*4+reg)=key-in-tile
        *(f32x4*)(sc + q15 * SC_STRW + w * 128 + t * 16 + quad * 4) = c * 0.125f;
    }
    __syncthreads();   // barrier 1: all sc written

    // ---- wave w loads ITS row w (bank=(8w+lane)%32 -> 2-way, free) ----
    unsigned u[32];
#pragma unroll
    for (int i = 0; i < 32; ++i) u[i] = f2ord(sc[w * SC_STRW + i * 64 + lane]);
    __syncthreads();   // barrier 2: sc dead everywhere -> P region reusable

    // ---- phase 2: exact select + softmax numerators -> P row w ----
    const unsigned T = radix_select(u);
    unsigned umx = 0;
#pragma unroll
    for (int i = 0; i < 32; ++i) umx = u[i] > umx ? u[i] : umx;
#pragma unroll
    for (int off = 32; off >= 1; off >>= 1) {
        const unsigned o = (unsigned)__shfl_xor((int)umx, off);
        umx = o > umx ? o : umx;
    }
    const float mx = ord2f(umx);
    float lsum = 0.f;
    unsigned short* Pr = P + w * P_STR;
#pragma unroll
    for (int i = 0; i < 32; ++i) {
        const float e = (u[i] >= T) ? __expf(ord2f(u[i]) - mx) : 0.f;
        Pr[i * 64 + lane] = f2bf(e);
        lsum += e;
    }
#pragma unroll
    for (int off = 32; off >= 1; off >>= 1) lsum += __shfl_xor(lsum, off);
    const float invd = 1.f / lsum;
    __syncthreads();   // barrier 3: all P rows visible

    // ---- phase 3: PV for keys [128w,+128), all 16 q (P reads & Opart
    //      writes hit disjoint LDS regions -> no barrier inside) ----
    {
        f32x4 oacc[4];
#pragma unroll
        for (int ht = 0; ht < 4; ++ht) oacc[ht] = (f32x4){0.f, 0.f, 0.f, 0.f};
        const size_t vtb = (size_t)bh * HDIM * S_LEN;
#pragma unroll
        for (int ks = 0; ks < 4; ++ks) {
            const int key0 = w * 128 + ks * 32 + quad * 8;
            const bf16x8 ap = *(const bf16x8*)(P + q15 * P_STR + key0);   // A[m=q][k]
#pragma unroll
            for (int ht = 0; ht < 4; ++ht) {
                const int hd = ht * 16 + q15;                             // B[k][n=hd]
                const bf16x8 bv = *(const bf16x8*)(Vt + vtb + (size_t)hd * S_LEN + key0);
                oacc[ht] = __builtin_amdgcn_mfma_f32_16x16x32_bf16(ap, bv, oacc[ht], 0, 0, 0);
            }
        }
        // D[m=q][n=hd]: col=lane&15=hd-in-tile, row=quad*4+reg=q
#pragma unroll
        for (int ht = 0; ht < 4; ++ht)
#pragma unroll
            for (int rg = 0; rg < 4; ++rg)
                Opart[w * 1024 + (quad * 4 + rg) * 64 + ht * 16 + q15] = oacc[ht][rg];
    }
    __syncthreads();   // barrier 4: all partials visible

    // ---- final: thread (r=w, hd=lane) reduces 16 partials of row w ----
    {
        float s = 0.f;
#pragma unroll
        for (int ww = 0; ww < 16; ++ww) s += Opart[ww * 1024 + w * 64 + lane];
        const float o = s * invd;   // invd belongs to row w == this wave
        const int b = bh >> 4, h = bh & 15;
        const size_t idx = ((size_t)(b * S_LEN + q0 + w)) * DMODEL + h * HDIM + lane;
        const unsigned short hh = f2bf(o);
        AOh[idx] = hh;
        AOl[idx] = f2bf(o - bf2f(hh));
    }
}

// ---------------------------------------------------------------------------
extern "C" void kernel_launch(void* const* d_in, const int* in_sizes, int n_in,
                              void* d_out, int out_size, void* d_ws, size_t ws_size,
                              hipStream_t stream)
{
    const float* X  = (const float*)d_in[0];
    const float* Wq = (const float*)d_in[1];
    const float* bq = (const float*)d_in[2];
    const float* Wk = (const float*)d_in[3];
    const float* bk = (const float*)d_in[4];
    const float* Wv = (const float*)d_in[5];
    const float* bv = (const float*)d_in[6];
    const float* Wo = (const float*)d_in[7];
    const float* bo = (const float*)d_in[8];

    char* p = (char*)d_ws;
    const size_t NEL = (size_t)BHC * S_LEN * HDIM;   // 4,194,304
    unsigned short* Q16h = (unsigned short*)p; p += NEL * 2;
    unsigned short* Q16l = (unsigned short*)p; p += NEL * 2;
    unsigned short* K16h = (unsigned short*)p; p += NEL * 2;
    unsigned short* K16l = (unsigned short*)p; p += NEL * 2;
    unsigned short* Vb16 = (unsigned short*)p; p += NEL * 2;
    unsigned short* Vt16 = (unsigned short*)p; p += NEL * 2;
    unsigned short* Xh   = (unsigned short*)p; p += NEL * 2;
    unsigned short* Xl   = (unsigned short*)p; p += NEL * 2;
    unsigned short* AOh  = (unsigned short*)p; p += NEL * 2;
    unsigned short* AOl  = (unsigned short*)p; p += NEL * 2;
    unsigned short* Wqh  = (unsigned short*)p; p += DMODEL * DMODEL * 2;
    unsigned short* Wql  = (unsigned short*)p; p += DMODEL * DMODEL * 2;
    unsigned short* Wkh  = (unsigned short*)p; p += DMODEL * DMODEL * 2;
    unsigned short* Wkl  = (unsigned short*)p; p += DMODEL * DMODEL * 2;
    unsigned short* Wvh  = (unsigned short*)p; p += DMODEL * DMODEL * 2;
    unsigned short* Wvl  = (unsigned short*)p; p += DMODEL * DMODEL * 2;
    unsigned short* Woh  = (unsigned short*)p; p += DMODEL * DMODEL * 2;
    unsigned short* Wol  = (unsigned short*)p; p += DMODEL * DMODEL * 2;

    const int attn_lds = 16 * SC_STRW * 4;   // 131,584 B
    hipFuncSetAttribute((const void*)attn_kernel,
                        hipFuncAttributeMaxDynamicSharedMemorySize, attn_lds);

    const int X4 = (int)(NEL / 4);                 // 1,048,576
    const int W4 = DMODEL * DMODEL / 4;            //   262,144

    // ---- input splits ----
    split32<<<(X4 + 255) / 256, 256, 0, stream>>>(X,  Xh,  Xl,  X4);
    split32<<<(W4 + 255) / 256, 256, 0, stream>>>(Wq, Wqh, Wql, W4);
    split32<<<(W4 + 255) / 256, 256, 0, stream>>>(Wk, Wkh, Wkl, W4);
    split32<<<(W4 + 255) / 256, 256, 0, stream>>>(Wv, Wvh, Wvl, W4);
    split32<<<(W4 + 255) / 256, 256, 0, stream>>>(Wo, Woh, Wol, W4);

    // ---- projections (LDS-staged MFMA split-bf16): tiles 128m x 64n ----
    const dim3 ggrid(16, 32, 1);
    gemm_mfma<<<ggrid, 256, 0, stream>>>(Xh, Xl, Wqh, Wql, bq, Q16h, Q16l, 2);
    gemm_mfma<<<ggrid, 256, 0, stream>>>(Xh, Xl, Wkh, Wkl, bk, K16h, K16l, 2);
    gemm_mfma<<<ggrid, 256, 0, stream>>>(Xh, Xl, Wvh, Wvl, bv, Vb16, nullptr, 3);
    transpose_v16<<<dim3(32, 32, 1), 256, 0, stream>>>(Vb16, Vt16);

    // ---- fused attention v7 (1024 thr, one row/wave, no spill) ----
    attn_kernel<<<4096, 1024, attn_lds, stream>>>(Q16h, Q16l, K16h, K16l, Vt16, AOh, AOl);

    // ---- output projection ----
    gemm_mfma<<<ggrid, 256, 0, stream>>>(AOh, AOl, Woh, Wol, bo, d_out, nullptr, 0);
}

// Round 10
// 899.324 us; speedup vs baseline: 1.0491x; 1.0491x over previous
//
#include <hip/hip_runtime.h>
#include <math.h>

#define S_LEN 2048
#define NH 16
#define HDIM 64
#define BATCH 2
#define BHC 32          // BATCH*NH
#define KK 409          // int(2048 * (1.0 - 0.8)) per reference float math
#define DMODEL 1024

typedef __attribute__((ext_vector_type(8))) short bf16x8;   // 8 bf16 in 4 VGPRs
typedef __attribute__((ext_vector_type(4))) float f32x4;

#define SC_STRW 2056    // fp32 score row stride in words
#define P_STR   2064    // bf16 P row stride (4128 B rows, 16B-aligned)
#define T_STR   40      // bf16 LDS tile row stride for gemm (16B-aligned, 2-way free)

__device__ __forceinline__ unsigned f2ord(float f) {
    unsigned u = __float_as_uint(f);
    return (u & 0x80000000u) ? ~u : (u | 0x80000000u);
}
__device__ __forceinline__ float ord2f(unsigned v) {
    unsigned u = (v & 0x80000000u) ? (v & 0x7fffffffu) : ~v;
    return __uint_as_float(u);
}
__device__ __forceinline__ unsigned short f2bf(float f) {   // RNE
    unsigned u = __float_as_uint(f);
    u += 0x7fffu + ((u >> 16) & 1u);
    return (unsigned short)(u >> 16);
}
__device__ __forceinline__ float bf2f(unsigned short h) {
    return __uint_as_float(((unsigned)h) << 16);
}

// ---------------------------------------------------------------------------
// fp32 -> bf16 hi/lo split (vectorized float4 / ushort4), n4 = elements/4
// ---------------------------------------------------------------------------
__global__ __launch_bounds__(256)
void split32(const float* __restrict__ in, unsigned short* __restrict__ hi,
             unsigned short* __restrict__ lo, int n4)
{
    const int i = blockIdx.x * 256 + threadIdx.x;
    if (i < n4) {
        const float4 v = ((const float4*)in)[i];
        ushort4 h, l;
        h.x = f2bf(v.x); l.x = f2bf(v.x - bf2f(h.x));
        h.y = f2bf(v.y); l.y = f2bf(v.y - bf2f(h.y));
        h.z = f2bf(v.z); l.z = f2bf(v.z - bf2f(h.z));
        h.w = f2bf(v.w); l.w = f2bf(v.w - bf2f(h.w));
        ((ushort4*)hi)[i] = h;
        ((ushort4*)lo)[i] = l;
    }
}

// ---------------------------------------------------------------------------
// LDS-staged split-bf16 3-pass MFMA GEMM (unchanged from R8 — banked).
//   C[m][n] = sum_k A[m][k]*B[n][k] + bias[n]
// ---------------------------------------------------------------------------
__global__ __launch_bounds__(256)
void gemm_mfma(const unsigned short* __restrict__ Ah, const unsigned short* __restrict__ Al,
               const unsigned short* __restrict__ Bh, const unsigned short* __restrict__ Bl,
               const float* __restrict__ bias, void* __restrict__ out0,
               void* __restrict__ out1, int mode)
{
    __shared__ __align__(16) unsigned short sAh[128 * T_STR];
    __shared__ __align__(16) unsigned short sAl[128 * T_STR];
    __shared__ __align__(16) unsigned short sBh[64 * T_STR];
    __shared__ __align__(16) unsigned short sBl[64 * T_STR];

    const int tid  = threadIdx.x;
    const int lane = tid & 63;
    const int w    = tid >> 6;
    const int q15  = lane & 15;
    const int quad = lane >> 4;
    const int n0b = blockIdx.x * 64;
    const int m0b = blockIdx.y * 128;
    const int wm = (w >> 1) * 64;
    const int wn = (w & 1) * 32;

    const int ar0 = tid >> 2, aks0 = (tid & 3) * 8;
    const int ar1 = (tid + 256) >> 2, aks1 = aks0;
    const int br = tid >> 2, bks = (tid & 3) * 8;

    const unsigned short* gAh0 = Ah + (size_t)(m0b + ar0) * 1024 + aks0;
    const unsigned short* gAh1 = Ah + (size_t)(m0b + ar1) * 1024 + aks1;
    const unsigned short* gAl0 = Al + (size_t)(m0b + ar0) * 1024 + aks0;
    const unsigned short* gAl1 = Al + (size_t)(m0b + ar1) * 1024 + aks1;
    const unsigned short* gBh = Bh + (size_t)(n0b + br) * 1024 + bks;
    const unsigned short* gBl = Bl + (size_t)(n0b + br) * 1024 + bks;

    f32x4 acc[4][2];
#pragma unroll
    for (int mt = 0; mt < 4; ++mt)
#pragma unroll
        for (int nt = 0; nt < 2; ++nt) acc[mt][nt] = (f32x4){0.f, 0.f, 0.f, 0.f};

#pragma unroll 1
    for (int k0 = 0; k0 < 1024; k0 += 32) {
        const bf16x8 vah0 = *(const bf16x8*)(gAh0 + k0);
        const bf16x8 vah1 = *(const bf16x8*)(gAh1 + k0);
        const bf16x8 val0 = *(const bf16x8*)(gAl0 + k0);
        const bf16x8 val1 = *(const bf16x8*)(gAl1 + k0);
        const bf16x8 vbh  = *(const bf16x8*)(gBh + k0);
        const bf16x8 vbl  = *(const bf16x8*)(gBl + k0);
        __syncthreads();
        *(bf16x8*)(sAh + ar0 * T_STR + aks0) = vah0;
        *(bf16x8*)(sAh + ar1 * T_STR + aks1) = vah1;
        *(bf16x8*)(sAl + ar0 * T_STR + aks0) = val0;
        *(bf16x8*)(sAl + ar1 * T_STR + aks1) = val1;
        *(bf16x8*)(sBh + br * T_STR + bks) = vbh;
        *(bf16x8*)(sBl + br * T_STR + bks) = vbl;
        __syncthreads();

        bf16x8 fbh[2], fbl[2];
#pragma unroll
        for (int nt = 0; nt < 2; ++nt) {
            fbh[nt] = *(const bf16x8*)(sBh + (wn + nt * 16 + q15) * T_STR + quad * 8);
            fbl[nt] = *(const bf16x8*)(sBl + (wn + nt * 16 + q15) * T_STR + quad * 8);
        }
#pragma unroll
        for (int mt = 0; mt < 4; ++mt) {
            const bf16x8 fah = *(const bf16x8*)(sAh + (wm + mt * 16 + q15) * T_STR + quad * 8);
            const bf16x8 fal = *(const bf16x8*)(sAl + (wm + mt * 16 + q15) * T_STR + quad * 8);
#pragma unroll
            for (int nt = 0; nt < 2; ++nt) {
                acc[mt][nt] = __builtin_amdgcn_mfma_f32_16x16x32_bf16(fah, fbh[nt], acc[mt][nt], 0, 0, 0);
                acc[mt][nt] = __builtin_amdgcn_mfma_f32_16x16x32_bf16(fah, fbl[nt], acc[mt][nt], 0, 0, 0);
                acc[mt][nt] = __builtin_amdgcn_mfma_f32_16x16x32_bf16(fal, fbh[nt], acc[mt][nt], 0, 0, 0);
            }
        }
    }

#pragma unroll
    for (int nt = 0; nt < 2; ++nt) {
        const int n = n0b + wn + nt * 16 + q15;
        const float bv = bias[n];
#pragma unroll
        for (int mt = 0; mt < 4; ++mt) {
            const int mb = m0b + wm + mt * 16 + quad * 4;
#pragma unroll
            for (int rg = 0; rg < 4; ++rg) {
                const int m = mb + rg;
                const float o = acc[mt][nt][rg] + bv;
                if (mode == 0) {
                    ((float*)out0)[(size_t)m * 1024 + n] = o;
                } else {
                    const int b = m >> 11, s = m & 2047;
                    const int h = n >> 6, hd = n & 63;
                    const size_t base = ((size_t)((b * NH + h) * S_LEN + s)) * HDIM + hd;
                    if (mode == 3) {
                        ((unsigned short*)out0)[base] = f2bf(o);
                    } else {
                        const unsigned short oh = f2bf(o);
                        ((unsigned short*)out0)[base] = oh;
                        ((unsigned short*)out1)[base] = f2bf(o - bf2f(oh));
                    }
                }
            }
        }
    }
}

// ---------------------------------------------------------------------------
// V bf16 [bh][s][64] -> Vt bf16 [bh][64][2048]  (B-operand layout for PV MFMA)
// ---------------------------------------------------------------------------
__global__ __launch_bounds__(256)
void transpose_v16(const unsigned short* __restrict__ V, unsigned short* __restrict__ Vt)
{
    __shared__ unsigned short t[64][72];
    const int tid = threadIdx.x;
    const int s0 = blockIdx.x * 64;
    const int bh = blockIdx.y;
    const unsigned short* Vb = V + (size_t)bh * S_LEN * HDIM;
#pragma unroll
    for (int i = 0; i < 4; ++i) {
        const int f = tid + i * 256;
        const int s = f >> 4;
        const int hq = (f & 15) * 4;
        const ushort4 v = *(const ushort4*)(Vb + (size_t)(s0 + s) * HDIM + hq);
        t[s][hq + 0] = v.x; t[s][hq + 1] = v.y; t[s][hq + 2] = v.z; t[s][hq + 3] = v.w;
    }
    __syncthreads();
    unsigned short* Vtb = Vt + (size_t)bh * HDIM * S_LEN;
#pragma unroll
    for (int i = 0; i < 4; ++i) {
        const int f = tid + i * 256;
        const int hd = f >> 4;
        const int sq = (f & 15) * 4;
        ushort4 v;
        v.x = t[sq + 0][hd]; v.y = t[sq + 1][hd];
        v.z = t[sq + 2][hd]; v.w = t[sq + 3][hd];
        *(ushort4*)(Vtb + (size_t)hd * S_LEN + s0 + sq) = v;
    }
}

// ---------------------------------------------------------------------------
// Exact 409th-largest over 2048 ordered uints held as u[32] per lane.
// RANK-COUNT binary search on the answer: per bit, count #{u >= T|1<<b}
// with ONE v_cmp per element (uniform scalar threshold; ballot+popcount on
// SALU). If cnt >= K the bit is 1. Early exit when cnt == K: the top-K are
// exactly {u >= X}, so the k-th largest is their min.
// Bit-identical result to the prefix-radix version (pure rank counting;
// keep set {u >= T} includes ties, matching reference `attn < thr`).
// ---------------------------------------------------------------------------
__device__ __forceinline__ unsigned radix_select(const unsigned (&u)[32])
{
    unsigned T = 0;
#pragma unroll 1
    for (int b = 31; b >= 0; --b) {
        const unsigned X = T | (1u << b);
        int cnt = 0;
#pragma unroll
        for (int i = 0; i < 32; ++i)
            cnt += __builtin_popcountll(__ballot(u[i] >= X));
        if (cnt >= KK) {
            T = X;
            if (cnt == KK) {   // answer = min over {u >= X}
                unsigned mn = 0xffffffffu;
#pragma unroll
                for (int i = 0; i < 32; ++i) {
                    const unsigned v = (u[i] >= X) ? u[i] : 0xffffffffu;
                    mn = v < mn ? v : mn;
                }
#pragma unroll
                for (int off = 32; off >= 1; off >>= 1) {
                    const unsigned o = (unsigned)__shfl_xor((int)mn, off);
                    mn = o < mn ? o : mn;
                }
                return mn;
            }
        }
    }
    return T;
}

// ---------------------------------------------------------------------------
// Fused attention v8 = v7 (R9, passing) + rank-count select.
// 1024 threads / 16 waves; block = (bh, 16 q-rows); one q-row per wave ->
// u[32] constant-indexed, no scratch spill (verified R9: FETCH 20 MB).
// LDS 131,584 B: sc[16][2056]f32 overlaid by P[16][2064]bf16 (66,048 B) +
// Opart[16][16][64]f32 (65,536 B at offset 66,048) — disjoint, 4 barriers.
// ---------------------------------------------------------------------------
__global__ __launch_bounds__(1024, 4)
void attn_kernel(const unsigned short* __restrict__ Qh, const unsigned short* __restrict__ Ql,
                 const unsigned short* __restrict__ Kh, const unsigned short* __restrict__ Kl,
                 const unsigned short* __restrict__ Vt,
                 unsigned short* __restrict__ AOh, unsigned short* __restrict__ AOl)
{
    extern __shared__ __align__(16) char smem[];
    float* sc = (float*)smem;                            // [16][SC_STRW] f32
    unsigned short* P = (unsigned short*)smem;           // overlay [16][P_STR] bf16
    float* Opart = (float*)(smem + 66048);               // [16][16][64] f32

    const int tid  = threadIdx.x;
    const int lane = tid & 63;
    const int w    = tid >> 6;        // wave id == owned q-row
    const int q15  = lane & 15;
    const int quad = lane >> 4;

    // XCD swizzle: each XCD works one head at a time -> ~1.75 MB, L2-resident.
    const int blk = blockIdx.x;
    const int xcd = blk & 7;
    const int j   = blk >> 3;              // 0..511
    const int bh  = xcd * 4 + (j >> 7);    // 0..31
    const int q0  = (j & 127) * 16;        // 0..2032

    // ---- Q B-frags direct from global ----
    const size_t qrow = ((size_t)bh * S_LEN + q0 + q15) * HDIM;
    const bf16x8 bqh0 = *(const bf16x8*)(Qh + qrow + quad * 8);
    const bf16x8 bqh1 = *(const bf16x8*)(Qh + qrow + 32 + quad * 8);
    const bf16x8 bql0 = *(const bf16x8*)(Ql + qrow + quad * 8);
    const bf16x8 bql1 = *(const bf16x8*)(Ql + qrow + 32 + quad * 8);

    const size_t kbase = (size_t)bh * S_LEN * HDIM;

    // ---- phase 1: scores for key-span [128w, 128w+128), all 16 q-rows ----
#pragma unroll 2
    for (int t = 0; t < 8; ++t) {
        const int key = w * 128 + t * 16 + q15;            // A-frag m
        const unsigned short* kh = Kh + kbase + (size_t)key * HDIM + quad * 8;
        const unsigned short* kl = Kl + kbase + (size_t)key * HDIM + quad * 8;
        const bf16x8 akh0 = *(const bf16x8*)(kh);
        const bf16x8 akh1 = *(const bf16x8*)(kh + 32);
        const bf16x8 akl0 = *(const bf16x8*)(kl);
        const bf16x8 akl1 = *(const bf16x8*)(kl + 32);
        f32x4 c = {0.f, 0.f, 0.f, 0.f};
        c = __builtin_amdgcn_mfma_f32_16x16x32_bf16(akh0, bqh0, c, 0, 0, 0);
        c = __builtin_amdgcn_mfma_f32_16x16x32_bf16(akh1, bqh1, c, 0, 0, 0);
        c = __builtin_amdgcn_mfma_f32_16x16x32_bf16(akh0, bql0, c, 0, 0, 0);
        c = __builtin_amdgcn_mfma_f32_16x16x32_bf16(akh1, bql1, c, 0, 0, 0);
        c = __builtin_amdgcn_mfma_f32_16x16x32_bf16(akl0, bqh0, c, 0, 0, 0);
        c = __builtin_amdgcn_mfma_f32_16x16x32_bf16(akl1, bqh1, c, 0, 0, 0);
        // C-layout: col(lane&15)=q, row(quad*4+reg)=key-in-tile
        *(f32x4*)(sc + q15 * SC_STRW + w * 128 + t * 16 + quad * 4) = c * 0.125f;
    }
    __syncthreads();   // barrier 1: all sc written

    // ---- wave w loads ITS row w (stride-1 lanes -> 2-way, free) ----
    unsigned u[32];
#pragma unroll
    for (int i = 0; i < 32; ++i) u[i] = f2ord(sc[w * SC_STRW + i * 64 + lane]);
    __syncthreads();   // barrier 2: sc dead everywhere -> P region reusable

    // ---- phase 2: exact select + softmax numerators -> P row w ----
    const unsigned T = radix_select(u);
    unsigned umx = 0;
#pragma unroll
    for (int i = 0; i < 32; ++i) umx = u[i] > umx ? u[i] : umx;
#pragma unroll
    for (int off = 32; off >= 1; off >>= 1) {
        const unsigned o = (unsigned)__shfl_xor((int)umx, off);
        umx = o > umx ? o : umx;
    }
    const float mx = ord2f(umx);
    float lsum = 0.f;
    unsigned short* Pr = P + w * P_STR;
#pragma unroll
    for (int i = 0; i < 32; ++i) {
        const float e = (u[i] >= T) ? __expf(ord2f(u[i]) - mx) : 0.f;
        Pr[i * 64 + lane] = f2bf(e);
        lsum += e;
    }
#pragma unroll
    for (int off = 32; off >= 1; off >>= 1) lsum += __shfl_xor(lsum, off);
    const float invd = 1.f / lsum;
    __syncthreads();   // barrier 3: all P rows visible

    // ---- phase 3: PV for keys [128w,+128), all 16 q ----
    {
        f32x4 oacc[4];
#pragma unroll
        for (int ht = 0; ht < 4; ++ht) oacc[ht] = (f32x4){0.f, 0.f, 0.f, 0.f};
        const size_t vtb = (size_t)bh * HDIM * S_LEN;
#pragma unroll
        for (int ks = 0; ks < 4; ++ks) {
            const int key0 = w * 128 + ks * 32 + quad * 8;
            const bf16x8 ap = *(const bf16x8*)(P + q15 * P_STR + key0);   // A[m=q][k]
#pragma unroll
            for (int ht = 0; ht < 4; ++ht) {
                const int hd = ht * 16 + q15;                             // B[k][n=hd]
                const bf16x8 bv = *(const bf16x8*)(Vt + vtb + (size_t)hd * S_LEN + key0);
                oacc[ht] = __builtin_amdgcn_mfma_f32_16x16x32_bf16(ap, bv, oacc[ht], 0, 0, 0);
            }
        }
        // D[m=q][n=hd]: col=lane&15=hd-in-tile, row=quad*4+reg=q
#pragma unroll
        for (int ht = 0; ht < 4; ++ht)
#pragma unroll
            for (int rg = 0; rg < 4; ++rg)
                Opart[w * 1024 + (quad * 4 + rg) * 64 + ht * 16 + q15] = oacc[ht][rg];
    }
    __syncthreads();   // barrier 4: all partials visible

    // ---- final: thread (r=w, hd=lane) reduces 16 partials of row w ----
    {
        float s = 0.f;
#pragma unroll
        for (int ww = 0; ww < 16; ++ww) s += Opart[ww * 1024 + w * 64 + lane];
        const float o = s * invd;   // invd belongs to row w == this wave
        const int b = bh >> 4, h = bh & 15;
        const size_t idx = ((size_t)(b * S_LEN + q0 + w)) * DMODEL + h * HDIM + lane;
        const unsigned short hh = f2bf(o);
        AOh[idx] = hh;
        AOl[idx] = f2bf(o - bf2f(hh));
    }
}

// ---------------------------------------------------------------------------
extern "C" void kernel_launch(void* const* d_in, const int* in_sizes, int n_in,
                              void* d_out, int out_size, void* d_ws, size_t ws_size,
                              hipStream_t stream)
{
    const float* X  = (const float*)d_in[0];
    const float* Wq = (const float*)d_in[1];
    const float* bq = (const float*)d_in[2];
    const float* Wk = (const float*)d_in[3];
    const float* bk = (const float*)d_in[4];
    const float* Wv = (const float*)d_in[5];
    const float* bv = (const float*)d_in[6];
    const float* Wo = (const float*)d_in[7];
    const float* bo = (const float*)d_in[8];

    char* p = (char*)d_ws;
    const size_t NEL = (size_t)BHC * S_LEN * HDIM;   // 4,194,304
    unsigned short* Q16h = (unsigned short*)p; p += NEL * 2;
    unsigned short* Q16l = (unsigned short*)p; p += NEL * 2;
    unsigned short* K16h = (unsigned short*)p; p += NEL * 2;
    unsigned short* K16l = (unsigned short*)p; p += NEL * 2;
    unsigned short* Vb16 = (unsigned short*)p; p += NEL * 2;
    unsigned short* Vt16 = (unsigned short*)p; p += NEL * 2;
    unsigned short* Xh   = (unsigned short*)p; p += NEL * 2;
    unsigned short* Xl   = (unsigned short*)p; p += NEL * 2;
    unsigned short* AOh  = (unsigned short*)p; p += NEL * 2;
    unsigned short* AOl  = (unsigned short*)p; p += NEL * 2;
    unsigned short* Wqh  = (unsigned short*)p; p += DMODEL * DMODEL * 2;
    unsigned short* Wql  = (unsigned short*)p; p += DMODEL * DMODEL * 2;
    unsigned short* Wkh  = (unsigned short*)p; p += DMODEL * DMODEL * 2;
    unsigned short* Wkl  = (unsigned short*)p; p += DMODEL * DMODEL * 2;
    unsigned short* Wvh  = (unsigned short*)p; p += DMODEL * DMODEL * 2;
    unsigned short* Wvl  = (unsigned short*)p; p += DMODEL * DMODEL * 2;
    unsigned short* Woh  = (unsigned short*)p; p += DMODEL * DMODEL * 2;
    unsigned short* Wol  = (unsigned short*)p; p += DMODEL * DMODEL * 2;

    const int attn_lds = 16 * SC_STRW * 4;   // 131,584 B
    hipFuncSetAttribute((const void*)attn_kernel,
                        hipFuncAttributeMaxDynamicSharedMemorySize, attn_lds);

    const int X4 = (int)(NEL / 4);                 // 1,048,576
    const int W4 = DMODEL * DMODEL / 4;            //   262,144

    // ---- input splits ----
    split32<<<(X4 + 255) / 256, 256, 0, stream>>>(X,  Xh,  Xl,  X4);
    split32<<<(W4 + 255) / 256, 256, 0, stream>>>(Wq, Wqh, Wql, W4);
    split32<<<(W4 + 255) / 256, 256, 0, stream>>>(Wk, Wkh, Wkl, W4);
    split32<<<(W4 + 255) / 256, 256, 0, stream>>>(Wv, Wvh, Wvl, W4);
    split32<<<(W4 + 255) / 256, 256, 0, stream>>>(Wo, Woh, Wol, W4);

    // ---- projections (LDS-staged MFMA split-bf16): tiles 128m x 64n ----
    const dim3 ggrid(16, 32, 1);
    gemm_mfma<<<ggrid, 256, 0, stream>>>(Xh, Xl, Wqh, Wql, bq, Q16h, Q16l, 2);
    gemm_mfma<<<ggrid, 256, 0, stream>>>(Xh, Xl, Wkh, Wkl, bk, K16h, K16l, 2);
    gemm_mfma<<<ggrid, 256, 0, stream>>>(Xh, Xl, Wvh, Wvl, bv, Vb16, nullptr, 3);
    transpose_v16<<<dim3(32, 32, 1), 256, 0, stream>>>(Vb16, Vt16);

    // ---- fused attention v8 (rank-count select) ----
    attn_kernel<<<4096, 1024, attn_lds, stream>>>(Q16h, Q16l, K16h, K16l, Vt16, AOh, AOl);

    // ---- output projection ----
    gemm_mfma<<<ggrid, 256, 0, stream>>>(AOh, AOl, Woh, Wol, bo, d_out, nullptr, 0);
}